// Round 1
// baseline (85.240 us; speedup 1.0000x reference)
//
#include <hip/hip_runtime.h>

namespace {

constexpr int kB  = 16;
constexpr int kF  = 4096;   // T_FEAT
constexpr int kD  = 512;
constexpr int kTT = 1024;   // T_TOK
constexpr int kC  = 64;             // chunks along F
constexpr int kCL = kF / kC;        // 64 frames per chunk
constexpr int kD4 = kD / 4;         // 128 float4 lanes per row

// ---------------- Phase 1: per-chunk sums ----------------
// thread id = ((b*kC + c)*kD4 + q); wave covers consecutive q -> coalesced 1KB
__global__ void chunk_sums_k(const float4* __restrict__ feats,
                             float4* __restrict__ S) {
    int tid = blockIdx.x * blockDim.x + threadIdx.x;
    int q = tid & (kD4 - 1);
    int c = (tid >> 7) & (kC - 1);
    int b = tid >> 13;
    const float4* p = feats + ((size_t)(b * kF + c * kCL)) * kD4 + q;
    float sx = 0.f, sy = 0.f, sz = 0.f, sw = 0.f;
#pragma unroll 8
    for (int i = 0; i < kCL; ++i) {
        float4 v = p[(size_t)i * kD4];
        sx += v.x; sy += v.y; sz += v.z; sw += v.w;
    }
    S[((size_t)(b * kC + c)) * kD4 + q] = make_float4(sx, sy, sz, sw);
}

// ---------------- Phase 2: exclusive scan of chunk sums ----------------
// thread id = b*kD4 + q ; serial over kC chunks (tiny: 4MB traffic)
__global__ void chunk_offsets_k(const float4* __restrict__ S,
                                float4* __restrict__ O) {
    int tid = blockIdx.x * blockDim.x + threadIdx.x;
    int q = tid & (kD4 - 1);
    int b = tid >> 7;
    float rx = 0.f, ry = 0.f, rz = 0.f, rw = 0.f;
    for (int c = 0; c < kC; ++c) {
        size_t idx = ((size_t)(b * kC + c)) * kD4 + q;
        float4 v = S[idx];
        O[idx] = make_float4(rx, ry, rz, rw);
        rx += v.x; ry += v.y; rz += v.z; rw += v.w;
    }
}

// ---------------- Phase 3: write inclusive prefix ----------------
__global__ void write_prefix_k(const float4* __restrict__ feats,
                               const float4* __restrict__ O,
                               float4* __restrict__ P) {
    int tid = blockIdx.x * blockDim.x + threadIdx.x;
    int q = tid & (kD4 - 1);
    int c = (tid >> 7) & (kC - 1);
    int b = tid >> 13;
    size_t base = ((size_t)(b * kF + c * kCL)) * kD4 + q;
    const float4* p = feats + base;
    float4* pp = P + base;
    float4 r = O[((size_t)(b * kC + c)) * kD4 + q];
#pragma unroll 4
    for (int i = 0; i < kCL; ++i) {
        float4 v = p[(size_t)i * kD4];
        r.x += v.x; r.y += v.y; r.z += v.z; r.w += v.w;
        pp[(size_t)i * kD4] = r;
    }
}

// ---------------- Phase 4: per-token gather ----------------
// one block (128 threads) per token; P[end] - P[start-1], divide by count
__global__ void gather_k(const float4* __restrict__ P,
                         const int* __restrict__ flens,
                         const int* __restrict__ tlens,
                         const float2* __restrict__ aligns,
                         float4* __restrict__ out,
                         float* __restrict__ out_lens) {
    int blk = blockIdx.x;            // b*kTT + t
    int t = blk & (kTT - 1);
    int b = blk >> 10;
    int q = threadIdx.x;             // 0..127
    int tlen = tlens[b];
    float fl = (float)flens[b];
    float2 a = aligns[blk];
    int s = (int)(a.x * fl);         // trunc toward zero, matches .astype(int32)
    int e = (int)(a.y * fl);
    if (e > kF - 1) e = kF - 1;
    int cnt = e - s + 1;
    float4 res = make_float4(0.f, 0.f, 0.f, 0.f);
    if (t < tlen && cnt > 0 && s < kF) {
        float4 hi = P[((size_t)(b * kF + e)) * kD4 + q];
        float4 lo = make_float4(0.f, 0.f, 0.f, 0.f);
        if (s > 0) lo = P[((size_t)(b * kF + s - 1)) * kD4 + q];
        float fc = (float)cnt;
        res = make_float4((hi.x - lo.x) / fc, (hi.y - lo.y) / fc,
                          (hi.z - lo.z) / fc, (hi.w - lo.w) / fc);
    }
    out[((size_t)blk) * kD4 + q] = res;
    if (t == 0 && q == 0) out_lens[b] = (float)tlen;
}

// ---------------- Fallback: direct summation (if ws too small) ----------------
__global__ void direct_k(const float4* __restrict__ feats,
                         const int* __restrict__ flens,
                         const int* __restrict__ tlens,
                         const float2* __restrict__ aligns,
                         float4* __restrict__ out,
                         float* __restrict__ out_lens) {
    int blk = blockIdx.x;
    int t = blk & (kTT - 1);
    int b = blk >> 10;
    int q = threadIdx.x;
    int tlen = tlens[b];
    float fl = (float)flens[b];
    float2 a = aligns[blk];
    int s = (int)(a.x * fl);
    int e = (int)(a.y * fl);
    if (e > kF - 1) e = kF - 1;
    int cnt = e - s + 1;
    float4 res = make_float4(0.f, 0.f, 0.f, 0.f);
    if (t < tlen && cnt > 0 && s < kF) {
        const float4* p = feats + ((size_t)(b * kF + s)) * kD4 + q;
        float sx = 0.f, sy = 0.f, sz = 0.f, sw = 0.f;
        for (int i = 0; i < cnt; ++i) {
            float4 v = p[(size_t)i * kD4];
            sx += v.x; sy += v.y; sz += v.z; sw += v.w;
        }
        float fc = (float)cnt;
        res = make_float4(sx / fc, sy / fc, sz / fc, sw / fc);
    }
    out[((size_t)blk) * kD4 + q] = res;
    if (t == 0 && q == 0) out_lens[b] = (float)tlen;
}

} // namespace

extern "C" void kernel_launch(void* const* d_in, const int* in_sizes, int n_in,
                              void* d_out, int out_size, void* d_ws, size_t ws_size,
                              hipStream_t stream) {
    const float4* feats  = (const float4*)d_in[0];            // [B, F, D] f32
    const int*    flens  = (const int*)d_in[1];               // [B]
    // d_in[2]: asr_token_ids (int64) -- unused by the computation
    const int*    tlens  = (const int*)d_in[3];               // [B]
    const float2* aligns = (const float2*)d_in[4];            // [B, TT, 2] f32

    float* out      = (float*)d_out;                          // [B, TT, D] then [B] lengths
    float* out_lens = out + (size_t)kB * kTT * kD;

    const size_t needP = (size_t)kB * kF * kD * sizeof(float);      // 128 MiB
    const size_t needS = (size_t)kB * kC * kD * sizeof(float);      // 2 MiB

    if (ws_size >= needP + 2 * needS) {
        float4* P = (float4*)d_ws;
        float4* S = (float4*)((char*)d_ws + needP);
        float4* O = (float4*)((char*)d_ws + needP + needS);

        int n1 = kB * kC * kD4;                                // 131072
        chunk_sums_k<<<n1 / 256, 256, 0, stream>>>(feats, S);
        int n2 = kB * kD4;                                     // 2048
        chunk_offsets_k<<<n2 / 256, 256, 0, stream>>>(S, O);
        write_prefix_k<<<n1 / 256, 256, 0, stream>>>(feats, O, P);
        gather_k<<<kB * kTT, kD4, 0, stream>>>(P, flens, tlens, aligns, (float4*)out, out_lens);
    } else {
        direct_k<<<kB * kTT, kD4, 0, stream>>>(feats, flens, tlens, aligns, (float4*)out, out_lens);
    }
}

// Round 2
// 50.887 us; speedup vs baseline: 1.6751x; 1.6751x over previous
//
#include <hip/hip_runtime.h>

namespace {

constexpr int kB  = 16;
constexpr int kF  = 4096;   // T_FEAT
constexpr int kD  = 512;
constexpr int kTT = 1024;   // T_TOK
constexpr int kC  = 64;     // 64-row chunks along F
constexpr int kJ  = 8;      // 8 sub-blocks of 8 rows per chunk
constexpr int kD4 = kD / 4; // 128 float4 lanes per row

__device__ inline void acc4(float4& a, const float4& v) {
    a.x += v.x; a.y += v.y; a.z += v.z; a.w += v.w;
}
__device__ inline void sub4(float4& a, const float4& v) {
    a.x -= v.x; a.y -= v.y; a.z -= v.z; a.w -= v.w;
}

// ---------------- K1: per-chunk internal inclusive prefixes at 8-row granularity
// thread per (b, c, q): sums 64 rows, writing running total every 8 rows.
// PS8[b][c][j][q] = sum of rows [c*64 .. c*64 + (j+1)*8 - 1]
__global__ void chunk_ps8_k(const float4* __restrict__ feats,
                            float4* __restrict__ PS8) {
    int tid = blockIdx.x * blockDim.x + threadIdx.x;
    int q = tid & (kD4 - 1);
    int c = (tid >> 7) & (kC - 1);
    int b = tid >> 13;
    const float4* p = feats + ((size_t)(b * kF + c * 64)) * kD4 + q;
    float4* o = PS8 + ((size_t)((b * kC + c) * kJ)) * kD4 + q;
    float4 r = make_float4(0.f, 0.f, 0.f, 0.f);
    for (int j = 0; j < kJ; ++j) {
#pragma unroll
        for (int i = 0; i < 8; ++i) acc4(r, p[(size_t)(j * 8 + i) * kD4]);
        o[(size_t)j * kD4] = r;
    }
}

// ---------------- K2: exclusive scan of chunk totals (PS8[...,7,...]) -> O64
__global__ void chunk_offsets_k(const float4* __restrict__ PS8,
                                float4* __restrict__ O64) {
    int tid = blockIdx.x * blockDim.x + threadIdx.x;  // 2048 threads
    int q = tid & (kD4 - 1);
    int b = tid >> 7;
    float4 r = make_float4(0.f, 0.f, 0.f, 0.f);
    for (int c = 0; c < kC; ++c) {
        O64[((size_t)(b * kC + c)) * kD4 + q] = r;
        acc4(r, PS8[((size_t)((b * kC + c) * kJ + (kJ - 1))) * kD4 + q]);
    }
}

// inclusive prefix over rows 0..r for one float4 lane q
__device__ inline float4 prefix_at(const float4* __restrict__ feats,
                                   const float4* __restrict__ PS8,
                                   const float4* __restrict__ O64,
                                   int b, int r, int q) {
    int c = r >> 6;
    int j = (r >> 3) & 7;
    int t = r & 7;
    float4 acc = O64[((size_t)(b * kC + c)) * kD4 + q];
    const float4* base = feats + ((size_t)(b * kF + c * 64 + j * 8)) * kD4 + q;
    if (t >= 4) {
        // backward: PS8 through sub-block j, subtract rows r+1 .. end of sub-block
        acc4(acc, PS8[((size_t)((b * kC + c) * kJ + j)) * kD4 + q]);
        for (int i = t + 1; i < 8; ++i) sub4(acc, base[(size_t)i * kD4]);
    } else {
        // forward: PS8 through sub-block j-1, add rows j*8 .. r
        if (j > 0) acc4(acc, PS8[((size_t)((b * kC + c) * kJ + j - 1)) * kD4 + q]);
        for (int i = 0; i <= t; ++i) acc4(acc, base[(size_t)i * kD4]);
    }
    return acc;
}

// ---------------- K3: per-token gather (1 block of 128 threads per token)
__global__ void gather_k(const float4* __restrict__ feats,
                         const float4* __restrict__ PS8,
                         const float4* __restrict__ O64,
                         const int* __restrict__ flens,
                         const int* __restrict__ tlens,
                         const float2* __restrict__ aligns,
                         float4* __restrict__ out,
                         float* __restrict__ out_lens) {
    int blk = blockIdx.x;            // b*kTT + t
    int t = blk & (kTT - 1);
    int b = blk >> 10;
    int q = threadIdx.x;             // 0..127
    int tlen = tlens[b];
    float fl = (float)flens[b];
    float2 a = aligns[blk];
    int s = (int)(a.x * fl);         // trunc toward zero == .astype(int32)
    int e = (int)(a.y * fl);
    if (e > kF - 1) e = kF - 1;
    int cnt = e - s + 1;
    float4 res = make_float4(0.f, 0.f, 0.f, 0.f);
    if (t < tlen && cnt > 0 && s < kF) {
        float4 hi = prefix_at(feats, PS8, O64, b, e, q);
        float4 lo = make_float4(0.f, 0.f, 0.f, 0.f);
        if (s > 0) lo = prefix_at(feats, PS8, O64, b, s - 1, q);
        float fc = (float)cnt;
        res = make_float4((hi.x - lo.x) / fc, (hi.y - lo.y) / fc,
                          (hi.z - lo.z) / fc, (hi.w - lo.w) / fc);
    }
    out[((size_t)blk) * kD4 + q] = res;
    if (t == 0 && q == 0) out_lens[b] = (float)tlen;
}

// ---------------- Fallback: direct summation (if ws too small) ----------------
__global__ void direct_k(const float4* __restrict__ feats,
                         const int* __restrict__ flens,
                         const int* __restrict__ tlens,
                         const float2* __restrict__ aligns,
                         float4* __restrict__ out,
                         float* __restrict__ out_lens) {
    int blk = blockIdx.x;
    int t = blk & (kTT - 1);
    int b = blk >> 10;
    int q = threadIdx.x;
    int tlen = tlens[b];
    float fl = (float)flens[b];
    float2 a = aligns[blk];
    int s = (int)(a.x * fl);
    int e = (int)(a.y * fl);
    if (e > kF - 1) e = kF - 1;
    int cnt = e - s + 1;
    float4 res = make_float4(0.f, 0.f, 0.f, 0.f);
    if (t < tlen && cnt > 0 && s < kF) {
        const float4* p = feats + ((size_t)(b * kF + s)) * kD4 + q;
        float4 r = make_float4(0.f, 0.f, 0.f, 0.f);
        for (int i = 0; i < cnt; ++i) acc4(r, p[(size_t)i * kD4]);
        float fc = (float)cnt;
        res = make_float4(r.x / fc, r.y / fc, r.z / fc, r.w / fc);
    }
    out[((size_t)blk) * kD4 + q] = res;
    if (t == 0 && q == 0) out_lens[b] = (float)tlen;
}

} // namespace

extern "C" void kernel_launch(void* const* d_in, const int* in_sizes, int n_in,
                              void* d_out, int out_size, void* d_ws, size_t ws_size,
                              hipStream_t stream) {
    const float4* feats  = (const float4*)d_in[0];            // [B, F, D] f32
    const int*    flens  = (const int*)d_in[1];               // [B]
    // d_in[2]: asr_token_ids (int64) -- unused
    const int*    tlens  = (const int*)d_in[3];               // [B]
    const float2* aligns = (const float2*)d_in[4];            // [B, TT, 2] f32

    float* out      = (float*)d_out;                          // [B, TT, D] then [B] lengths
    float* out_lens = out + (size_t)kB * kTT * kD;

    const size_t needPS8 = (size_t)kB * kC * kJ * kD * sizeof(float);  // 16 MiB
    const size_t needO64 = (size_t)kB * kC * kD * sizeof(float);       // 2 MiB

    if (ws_size >= needPS8 + needO64) {
        float4* PS8 = (float4*)d_ws;
        float4* O64 = (float4*)((char*)d_ws + needPS8);

        int n1 = kB * kC * kD4;                                // 131072
        chunk_ps8_k<<<n1 / 256, 256, 0, stream>>>(feats, PS8);
        int n2 = kB * kD4;                                     // 2048
        chunk_offsets_k<<<n2 / 256, 256, 0, stream>>>(PS8, O64);
        gather_k<<<kB * kTT, kD4, 0, stream>>>(feats, PS8, O64, flens, tlens, aligns,
                                               (float4*)out, out_lens);
    } else {
        direct_k<<<kB * kTT, kD4, 0, stream>>>(feats, flens, tlens, aligns,
                                               (float4*)out, out_lens);
    }
}

// Round 3
// 48.056 us; speedup vs baseline: 1.7738x; 1.0589x over previous
//
#include <hip/hip_runtime.h>

namespace {

constexpr int kB  = 16;
constexpr int kF  = 4096;   // T_FEAT
constexpr int kD  = 512;
constexpr int kTT = 1024;   // T_TOK
constexpr int kC  = 64;     // 64-row chunks along F
constexpr int kJ  = 8;      // 8 sub-blocks of 8 rows per chunk
constexpr int kD4 = kD / 4; // 128 float4 lanes per row

__device__ inline void acc4(float4& a, const float4& v) {
    a.x += v.x; a.y += v.y; a.z += v.z; a.w += v.w;
}
__device__ inline void sub4(float4& a, const float4& v) {
    a.x -= v.x; a.y -= v.y; a.z -= v.z; a.w -= v.w;
}

// ---------------- K1: per-chunk internal inclusive prefixes at 8-row granularity
// Length-aware: rows >= flen[b] are treated as ZERO (they are never inside any
// segment since e = trunc(a*flen) <= flen-1).
// PS8[b][c][j][q] = sum over valid rows in [c*64 .. c*64+(j+1)*8-1]
__global__ void chunk_ps8_k(const float4* __restrict__ feats,
                            const int* __restrict__ flens,
                            float4* __restrict__ PS8) {
    int tid = blockIdx.x * blockDim.x + threadIdx.x;
    int q = tid & (kD4 - 1);
    int c = (tid >> 7) & (kC - 1);
    int b = tid >> 13;
    int flen = flens[b];
    int base_row = c * 64;
    float4* o = PS8 + ((size_t)((b * kC + c) * kJ)) * kD4 + q;
    if (base_row >= flen) {
        float4 z = make_float4(0.f, 0.f, 0.f, 0.f);
#pragma unroll
        for (int j = 0; j < kJ; ++j) o[(size_t)j * kD4] = z;
        return;
    }
    const float4* p = feats + ((size_t)(b * kF + base_row)) * kD4 + q;
    float4 r = make_float4(0.f, 0.f, 0.f, 0.f);
    if (base_row + 64 <= flen) {          // fully valid chunk: fast path
        for (int j = 0; j < kJ; ++j) {
#pragma unroll
            for (int i = 0; i < 8; ++i) acc4(r, p[(size_t)(j * 8 + i) * kD4]);
            o[(size_t)j * kD4] = r;
        }
    } else {                               // straddling chunk: masked accumulate
        int nvalid = flen - base_row;      // 1..63
        for (int j = 0; j < kJ; ++j) {
            for (int i = 0; i < 8; ++i) {
                int row = j * 8 + i;
                if (row < nvalid) acc4(r, p[(size_t)row * kD4]);
            }
            o[(size_t)j * kD4] = r;
        }
    }
}

// ---------------- K2: exclusive scan of chunk totals -> O64 (scalar lanes, 8192 thr)
__global__ void chunk_offsets_k(const float* __restrict__ PS8,
                                float* __restrict__ O64) {
    int tid = blockIdx.x * blockDim.x + threadIdx.x;  // kB*kD = 8192
    int d = tid & (kD - 1);
    int b = tid >> 9;
    float r = 0.f;
    for (int c = 0; c < kC; ++c) {
        O64[((size_t)(b * kC + c)) * kD + d] = r;
        r += PS8[((size_t)((b * kC + c) * kJ + (kJ - 1))) * kD + d];
    }
}

// inclusive prefix over valid rows 0..r for one float4 lane q
__device__ inline float4 prefix_at(const float4* __restrict__ feats,
                                   const float4* __restrict__ PS8,
                                   const float4* __restrict__ O64,
                                   int b, int r, int q, int flen) {
    int c = r >> 6;
    int j = (r >> 3) & 7;
    int t = r & 7;
    int blk_start = c * 64 + j * 8;
    float4 acc = O64[((size_t)(b * kC + c)) * kD4 + q];
    const float4* base = feats + ((size_t)(b * kF + blk_start)) * kD4 + q;
    if (t >= 4) {
        // backward: PS8 through sub-block j, subtract valid rows r+1 .. end
        acc4(acc, PS8[((size_t)((b * kC + c) * kJ + j)) * kD4 + q]);
        int lim = flen - blk_start;            // valid rows in this sub-block
        if (lim > 8) lim = 8;
        for (int i = t + 1; i < lim; ++i) sub4(acc, base[(size_t)i * kD4]);
    } else {
        // forward: PS8 through sub-block j-1, add rows blk_start .. r
        if (j > 0) acc4(acc, PS8[((size_t)((b * kC + c) * kJ + j - 1)) * kD4 + q]);
        for (int i = 0; i <= t; ++i) acc4(acc, base[(size_t)i * kD4]);
    }
    return acc;
}

// ---------------- K3: per-token gather (1 block of 128 threads per token)
__global__ void gather_k(const float4* __restrict__ feats,
                         const float4* __restrict__ PS8,
                         const float4* __restrict__ O64,
                         const int* __restrict__ flens,
                         const int* __restrict__ tlens,
                         const float2* __restrict__ aligns,
                         float4* __restrict__ out,
                         float* __restrict__ out_lens) {
    int blk = blockIdx.x;            // b*kTT + t
    int t = blk & (kTT - 1);
    int b = blk >> 10;
    int q = threadIdx.x;             // 0..127
    int tlen = tlens[b];
    int flen = flens[b];
    float fl = (float)flen;
    float2 a = aligns[blk];
    int s = (int)(a.x * fl);         // trunc toward zero == .astype(int32)
    int e = (int)(a.y * fl);
    if (e > kF - 1) e = kF - 1;
    int cnt = e - s + 1;
    float4 res = make_float4(0.f, 0.f, 0.f, 0.f);
    if (t < tlen && cnt > 0 && s < kF) {
        float4 hi = prefix_at(feats, PS8, O64, b, e, q, flen);
        float4 lo = make_float4(0.f, 0.f, 0.f, 0.f);
        if (s > 0) lo = prefix_at(feats, PS8, O64, b, s - 1, q, flen);
        float fc = (float)cnt;
        res = make_float4((hi.x - lo.x) / fc, (hi.y - lo.y) / fc,
                          (hi.z - lo.z) / fc, (hi.w - lo.w) / fc);
    }
    out[((size_t)blk) * kD4 + q] = res;
    if (t == 0 && q == 0) out_lens[b] = (float)tlen;
}

// ---------------- Fallback: direct summation (if ws too small) ----------------
__global__ void direct_k(const float4* __restrict__ feats,
                         const int* __restrict__ flens,
                         const int* __restrict__ tlens,
                         const float2* __restrict__ aligns,
                         float4* __restrict__ out,
                         float* __restrict__ out_lens) {
    int blk = blockIdx.x;
    int t = blk & (kTT - 1);
    int b = blk >> 10;
    int q = threadIdx.x;
    int tlen = tlens[b];
    float fl = (float)flens[b];
    float2 a = aligns[blk];
    int s = (int)(a.x * fl);
    int e = (int)(a.y * fl);
    if (e > kF - 1) e = kF - 1;
    int cnt = e - s + 1;
    float4 res = make_float4(0.f, 0.f, 0.f, 0.f);
    if (t < tlen && cnt > 0 && s < kF) {
        const float4* p = feats + ((size_t)(b * kF + s)) * kD4 + q;
        float4 r = make_float4(0.f, 0.f, 0.f, 0.f);
        for (int i = 0; i < cnt; ++i) acc4(r, p[(size_t)i * kD4]);
        float fc = (float)cnt;
        res = make_float4(r.x / fc, r.y / fc, r.z / fc, r.w / fc);
    }
    out[((size_t)blk) * kD4 + q] = res;
    if (t == 0 && q == 0) out_lens[b] = (float)tlen;
}

} // namespace

extern "C" void kernel_launch(void* const* d_in, const int* in_sizes, int n_in,
                              void* d_out, int out_size, void* d_ws, size_t ws_size,
                              hipStream_t stream) {
    const float4* feats  = (const float4*)d_in[0];            // [B, F, D] f32
    const int*    flens  = (const int*)d_in[1];               // [B]
    // d_in[2]: asr_token_ids (int64) -- unused
    const int*    tlens  = (const int*)d_in[3];               // [B]
    const float2* aligns = (const float2*)d_in[4];            // [B, TT, 2] f32

    float* out      = (float*)d_out;                          // [B, TT, D] then [B] lengths
    float* out_lens = out + (size_t)kB * kTT * kD;

    const size_t needPS8 = (size_t)kB * kC * kJ * kD * sizeof(float);  // 16 MiB
    const size_t needO64 = (size_t)kB * kC * kD * sizeof(float);       // 2 MiB

    if (ws_size >= needPS8 + needO64) {
        float4* PS8 = (float4*)d_ws;
        float4* O64 = (float4*)((char*)d_ws + needPS8);

        int n1 = kB * kC * kD4;                                // 131072
        chunk_ps8_k<<<n1 / 256, 256, 0, stream>>>(feats, flens, PS8);
        int n2 = kB * kD;                                      // 8192 scalar lanes
        chunk_offsets_k<<<n2 / 256, 256, 0, stream>>>((const float*)PS8, (float*)O64);
        gather_k<<<kB * kTT, kD4, 0, stream>>>(feats, PS8, O64, flens, tlens, aligns,
                                               (float4*)out, out_lens);
    } else {
        direct_k<<<kB * kTT, kD4, 0, stream>>>(feats, flens, tlens, aligns,
                                               (float4*)out, out_lens);
    }
}

// Round 4
// 41.336 us; speedup vs baseline: 2.0621x; 1.1625x over previous
//
#include <hip/hip_runtime.h>
#include <hip/hip_fp16.h>

namespace {

constexpr int kB  = 16;
constexpr int kF  = 4096;   // T_FEAT
constexpr int kD  = 512;
constexpr int kTT = 1024;   // T_TOK
constexpr int kC  = 64;     // 64-row chunks along F
constexpr int kD4 = kD / 4; // 128 float4 lanes per row

__device__ inline void acc4(float4& a, const float4& v) {
    a.x += v.x; a.y += v.y; a.z += v.z; a.w += v.w;
}

__device__ inline ushort4 pack_h4(const float4& v) {
    ushort4 u;
    u.x = __half_as_ushort(__float2half_rn(v.x));
    u.y = __half_as_ushort(__float2half_rn(v.y));
    u.z = __half_as_ushort(__float2half_rn(v.z));
    u.w = __half_as_ushort(__float2half_rn(v.w));
    return u;
}

__device__ inline float4 unpack_h4(const ushort4& u) {
    return make_float4(__half2float(__ushort_as_half(u.x)),
                       __half2float(__ushort_as_half(u.y)),
                       __half2float(__ushort_as_half(u.z)),
                       __half2float(__ushort_as_half(u.w)));
}

// ---------------- K1: per-chunk per-row inclusive prefix (fp16) + chunk totals (f32)
// Pc[b][r][d] (fp16) = sum of rows [c*64 .. r] within r's chunk  (chunk-local!)
// S[b][c][d]  (f32)  = total of chunk c's valid rows
// Rows >= flen[b] are never read downstream; skip them (length-aware).
__global__ void chunk_prefix_k(const float4* __restrict__ feats,
                               const int* __restrict__ flens,
                               ushort4* __restrict__ Pc,
                               float4* __restrict__ S) {
    int tid = blockIdx.x * blockDim.x + threadIdx.x;
    int q = tid & (kD4 - 1);
    int c = (tid >> 7) & (kC - 1);
    int b = tid >> 13;
    int flen = flens[b];
    int base_row = c * 64;
    float4 r = make_float4(0.f, 0.f, 0.f, 0.f);
    int nval = flen - base_row;
    size_t fbase = ((size_t)(b * kF + base_row)) * kD4 + q;
    if (nval > 0) {
        if (nval > 64) nval = 64;
        const float4* p = feats + fbase;
        ushort4* o = Pc + fbase;
        if (nval == 64) {
#pragma unroll 8
            for (int i = 0; i < 64; ++i) {
                acc4(r, p[(size_t)i * kD4]);
                o[(size_t)i * kD4] = pack_h4(r);
            }
        } else {
            for (int i = 0; i < nval; ++i) {
                acc4(r, p[(size_t)i * kD4]);
                o[(size_t)i * kD4] = pack_h4(r);
            }
        }
    }
    S[((size_t)(b * kC + c)) * kD4 + q] = r;
}

// ---------------- K2: exclusive scan of chunk totals -> O64 (f32, scalar lanes)
__global__ void chunk_offsets_k(const float* __restrict__ S,
                                float* __restrict__ O64) {
    int tid = blockIdx.x * blockDim.x + threadIdx.x;  // kB*kD = 8192
    int d = tid & (kD - 1);
    int b = tid >> 9;
    float r = 0.f;
    for (int c = 0; c < kC; ++c) {
        O64[((size_t)(b * kC + c)) * kD + d] = r;
        r += S[((size_t)(b * kC + c)) * kD + d];
    }
}

// global inclusive prefix at row r: O64[chunk(r)] + Pc[r]
__device__ inline float4 prefix_at(const ushort4* __restrict__ Pc,
                                   const float4* __restrict__ O64,
                                   int b, int r, int q) {
    float4 acc = O64[((size_t)(b * kC + (r >> 6))) * kD4 + q];
    float4 p = unpack_h4(Pc[((size_t)(b * kF + r)) * kD4 + q]);
    acc4(acc, p);
    return acc;
}

// ---------------- K3: per-token gather (1 block of 128 threads per token)
__global__ void gather_k(const ushort4* __restrict__ Pc,
                         const float4* __restrict__ O64,
                         const int* __restrict__ flens,
                         const int* __restrict__ tlens,
                         const float2* __restrict__ aligns,
                         float4* __restrict__ out,
                         float* __restrict__ out_lens) {
    int blk = blockIdx.x;            // b*kTT + t
    int t = blk & (kTT - 1);
    int b = blk >> 10;
    int q = threadIdx.x;             // 0..127
    int tlen = tlens[b];
    int flen = flens[b];
    float fl = (float)flen;
    float2 a = aligns[blk];
    int s = (int)(a.x * fl);         // trunc toward zero == .astype(int32)
    int e = (int)(a.y * fl);
    if (e > kF - 1) e = kF - 1;
    int cnt = e - s + 1;
    float4 res = make_float4(0.f, 0.f, 0.f, 0.f);
    if (t < tlen && cnt > 0 && s < kF) {
        int er = e;      if (er > flen - 1) er = flen - 1;   // Pc safety clamp
        float4 hi = prefix_at(Pc, O64, b, er, q);
        float4 lo = make_float4(0.f, 0.f, 0.f, 0.f);
        if (s > 0) {
            int sr = s - 1; if (sr > flen - 1) sr = flen - 1;
            lo = prefix_at(Pc, O64, b, sr, q);
        }
        float fc = (float)cnt;
        res = make_float4((hi.x - lo.x) / fc, (hi.y - lo.y) / fc,
                          (hi.z - lo.z) / fc, (hi.w - lo.w) / fc);
    }
    out[((size_t)blk) * kD4 + q] = res;
    if (t == 0 && q == 0) out_lens[b] = (float)tlen;
}

// ---------------- Fallback: direct summation (if ws too small) ----------------
__global__ void direct_k(const float4* __restrict__ feats,
                         const int* __restrict__ flens,
                         const int* __restrict__ tlens,
                         const float2* __restrict__ aligns,
                         float4* __restrict__ out,
                         float* __restrict__ out_lens) {
    int blk = blockIdx.x;
    int t = blk & (kTT - 1);
    int b = blk >> 10;
    int q = threadIdx.x;
    int tlen = tlens[b];
    float fl = (float)flens[b];
    float2 a = aligns[blk];
    int s = (int)(a.x * fl);
    int e = (int)(a.y * fl);
    if (e > kF - 1) e = kF - 1;
    int cnt = e - s + 1;
    float4 res = make_float4(0.f, 0.f, 0.f, 0.f);
    if (t < tlen && cnt > 0 && s < kF) {
        const float4* p = feats + ((size_t)(b * kF + s)) * kD4 + q;
        float4 r = make_float4(0.f, 0.f, 0.f, 0.f);
        for (int i = 0; i < cnt; ++i) acc4(r, p[(size_t)i * kD4]);
        float fc = (float)cnt;
        res = make_float4(r.x / fc, r.y / fc, r.z / fc, r.w / fc);
    }
    out[((size_t)blk) * kD4 + q] = res;
    if (t == 0 && q == 0) out_lens[b] = (float)tlen;
}

} // namespace

extern "C" void kernel_launch(void* const* d_in, const int* in_sizes, int n_in,
                              void* d_out, int out_size, void* d_ws, size_t ws_size,
                              hipStream_t stream) {
    const float4* feats  = (const float4*)d_in[0];            // [B, F, D] f32
    const int*    flens  = (const int*)d_in[1];               // [B]
    // d_in[2]: asr_token_ids (int64) -- unused
    const int*    tlens  = (const int*)d_in[3];               // [B]
    const float2* aligns = (const float2*)d_in[4];            // [B, TT, 2] f32

    float* out      = (float*)d_out;                          // [B, TT, D] then [B] lengths
    float* out_lens = out + (size_t)kB * kTT * kD;

    const size_t needPc  = (size_t)kB * kF * kD * sizeof(unsigned short); // 64 MiB
    const size_t needS   = (size_t)kB * kC * kD * sizeof(float);          // 2 MiB
    const size_t needO64 = needS;                                         // 2 MiB

    if (ws_size >= needPc + needS + needO64) {
        ushort4* Pc  = (ushort4*)d_ws;
        float4*  S   = (float4*)((char*)d_ws + needPc);
        float4*  O64 = (float4*)((char*)d_ws + needPc + needS);

        int n1 = kB * kC * kD4;                                // 131072
        chunk_prefix_k<<<n1 / 256, 256, 0, stream>>>(feats, flens, Pc, S);
        int n2 = kB * kD;                                      // 8192 scalar lanes
        chunk_offsets_k<<<n2 / 256, 256, 0, stream>>>((const float*)S, (float*)O64);
        gather_k<<<kB * kTT, kD4, 0, stream>>>(Pc, O64, flens, tlens, aligns,
                                               (float4*)out, out_lens);
    } else {
        direct_k<<<kB * kTT, kD4, 0, stream>>>(feats, flens, tlens, aligns,
                                               (float4*)out, out_lens);
    }
}